// Round 7
// baseline (383.894 us; speedup 1.0000x reference)
//
#include <hip/hip_runtime.h>
#include <math.h>

#pragma clang fp contract(off)

#define NLVL 5
#define TOTALN 261888
#define NBATCH 16
#define CAP 1024
#define NPROB (NBATCH * NLVL)
#define POST_N 1000
#define NMS_TH 0.7f
#define MINSZ 1e-3f
#define IMGSZ 1024.0f
#define BBOX_CLIP 4.135166556742356f

#define HBINS 2048
#define CCAP 4096
#define NCHUNK 256   // ceil(261888/1024); level offsets are all multiples of 1024

__constant__ int c_loff[NLVL] = {0, 196608, 245760, 258048, 261120};
__constant__ int c_num[NLVL]  = {196608, 49152, 12288, 3072, 768};
__constant__ int c_k[NLVL]    = {1000, 1000, 1000, 1000, 768};

__device__ __forceinline__ unsigned monokey(float f) {
    unsigned b = __float_as_uint(f);
    return (b & 0x80000000u) ? ~b : (b | 0x80000000u);
}

__device__ __forceinline__ int lvl_of_start(int start) {
    return (start >= 261120) ? 4 : (start >= 258048) ? 3 : (start >= 245760) ? 2
         : (start >= 196608) ? 1 : 0;
}

// ---------------- pass 1: per-chunk LDS histogram of top-11 key bits ----------------
__global__ __launch_bounds__(256) void hist_kernel(const float* __restrict__ obj_all,
                                                   unsigned* __restrict__ ghist) {
    __shared__ unsigned lh[HBINS];
    const int tid = threadIdx.x;
    const int chunk = blockIdx.x;
    const int img = chunk >> 8, c = chunk & 255;
    const int start = c << 10;
    const int lvl = lvl_of_start(start);
    const int nrem = min(1024, TOTALN - start);
    for (int i = tid; i < HBINS; i += 256) lh[i] = 0;
    __syncthreads();
    const float* o = obj_all + (size_t)img * TOTALN + start;
    for (int i = tid; i < nrem; i += 256) atomicAdd(&lh[monokey(o[i]) >> 21], 1u);
    __syncthreads();
    unsigned* gh = ghist + (size_t)(img * NLVL + lvl) * HBINS;
    for (int i = tid; i < HBINS; i += 256) {
        unsigned v = lh[i];
        if (v) atomicAdd(&gh[i], v);
    }
}

// ---------------- pick threshold bucket b1 per problem (suffix-sum of hist) ----------------
__global__ __launch_bounds__(256) void pick1_kernel(const unsigned* __restrict__ ghist,
                                                    unsigned* __restrict__ b1out) {
    __shared__ unsigned suf[HBINS];
    const int p = blockIdx.x, tid = threadIdx.x;
    const int k = c_k[p % NLVL];
    const unsigned* gh = ghist + (size_t)p * HBINS;
    for (int i = tid; i < HBINS; i += 256) suf[i] = gh[i];
    __syncthreads();
    for (int d = 1; d < HBINS; d <<= 1) {
        unsigned v[HBINS / 256];
#pragma unroll
        for (int r = 0; r < HBINS / 256; ++r) {
            int i = tid + r * 256;
            v[r] = suf[i] + ((i + d < HBINS) ? suf[i + d] : 0u);
        }
        __syncthreads();
#pragma unroll
        for (int r = 0; r < HBINS / 256; ++r) suf[tid + r * 256] = v[r];
        __syncthreads();
    }
#pragma unroll
    for (int r = 0; r < HBINS / 256; ++r) {
        int i = tid + r * 256;
        if (suf[i] >= (unsigned)k && (i == HBINS - 1 || suf[i + 1] < (unsigned)k))
            b1out[p] = (unsigned)i;
    }
}

// ---------------- pass 2: compact all keys >= (b1<<21) ----------------
__global__ __launch_bounds__(256) void compact_kernel(const float* __restrict__ obj_all,
                                                      const unsigned* __restrict__ b1in,
                                                      int* __restrict__ cnt,
                                                      unsigned long long* __restrict__ cand) {
    __shared__ unsigned long long lkey[1024];
    __shared__ int s_lc, s_base;
    const int tid = threadIdx.x;
    const int chunk = blockIdx.x;
    const int img = chunk >> 8, c = chunk & 255;
    const int start = c << 10;
    const int lvl = lvl_of_start(start);
    const int nrem = min(1024, TOTALN - start);
    const int p = img * NLVL + lvl;
    const unsigned thr = b1in[p] << 21;
    const int local0 = start - c_loff[lvl];
    if (tid == 0) s_lc = 0;
    __syncthreads();
    const float* o = obj_all + (size_t)img * TOTALN + start;
    for (int i = tid; i < nrem; i += 256) {
        unsigned key = monokey(o[i]);
        if (key >= thr) {
            int l = atomicAdd(&s_lc, 1);
            lkey[l] = (((unsigned long long)key) << 32) | (unsigned)(~(unsigned)(local0 + i));
        }
    }
    __syncthreads();
    if (tid == 0) s_base = atomicAdd(&cnt[p], s_lc);
    __syncthreads();
    const int lc = s_lc, base = s_base;
    unsigned long long* cd = cand + (size_t)p * CCAP;
    for (int i = tid; i < lc; i += 256) {
        int pos = base + i;
        if (pos < CCAP) cd[pos] = lkey[i];
    }
}

// ---------------- finalize via rank: pos_i = #{j : key_j > key_i}, barrier-free ----------------
__global__ __launch_bounds__(256) void rank_kernel(const unsigned long long* __restrict__ cand,
                                                   const int* __restrict__ cnt,
                                                   unsigned* __restrict__ sel) {
    __shared__ unsigned long long skey[CCAP];
    const int p = blockIdx.x >> 4;
    const int blk = blockIdx.x & 15;
    const int tid = threadIdx.x;
    const int lvl = p % NLVL, k = c_k[lvl];
    int n = cnt[p]; if (n > CCAP) n = CCAP;
    const int i0 = blk << 8;
    if (i0 >= n) return;                       // block-uniform exit, no barrier crossed
    const unsigned long long* cd = cand + (size_t)p * CCAP;
    const int n8 = (n + 7) & ~7;
    for (int i = tid; i < n8; i += 256) skey[i] = (i < n) ? cd[i] : 0ull;
    __syncthreads();
    const int i = i0 + tid;
    const unsigned long long my = (i < n) ? skey[i] : ~0ull;  // sentinel -> rank 0, not emitted
    int rank = 0;
    for (int j = 0; j < n8; j += 8) {          // wave-uniform LDS broadcast reads
        unsigned long long k0 = skey[j + 0], k1 = skey[j + 1];
        unsigned long long k2 = skey[j + 2], k3 = skey[j + 3];
        unsigned long long k4 = skey[j + 4], k5 = skey[j + 5];
        unsigned long long k6 = skey[j + 6], k7 = skey[j + 7];
        rank += (int)(k0 > my) + (int)(k1 > my) + (int)(k2 > my) + (int)(k3 > my)
              + (int)(k4 > my) + (int)(k5 > my) + (int)(k6 > my) + (int)(k7 > my);
    }
    if (i < n && rank < k) {
        unsigned li = ~(unsigned)(my & 0xFFFFFFFFull);
        sel[p * CAP + rank] = (unsigned)c_loff[lvl] + li;
    }
}

// ---------------- fused decode + mask + serial scan, mask entirely in LDS ----------------
// LDS: mask 128 KB (rotate-swizzled columns: word w of row i lives at [i][(w+i)&15]),
// boxes/scores 24 KB, survivor list 2 KB -> 157.7 KB of the 160 KB pool, 1 block/CU.
// Swizzle effects: row writes & diagonal reads 4-way (≈free), per-accept row reads
// (lane wsel reads word wsel of one row) land on 16 distinct bank-pairs -> conflict-free.
// Sub-diagonal words are never written: they only pollute rem words that were already
// consumed (rem word w is read exactly once, at the start of group w).
__global__ __launch_bounds__(1024) void nms_fused_kernel(
    const float* __restrict__ obj_all, const float* __restrict__ deltas,
    const float* __restrict__ anchors, const unsigned* __restrict__ sel,
    float* __restrict__ svbox, float* __restrict__ svsc, int* __restrict__ svcnt) {
    __shared__ unsigned long long lmask[CAP][16];
    __shared__ float sx1[CAP], sy1[CAP], sx2[CAP], sy2[CAP], sar[CAP], ssc[CAP];
    __shared__ unsigned short survL[CAP];
    __shared__ int s_ns;

    const int p = blockIdx.x;
    const int img = p / NLVL, lvl = p % NLVL;
    const int k = c_k[lvl];
    const int tid = threadIdx.x;
    const int base = p * CAP;

    // ---- decode + clip + validity + sigmoid (thread = its own row) ----
    {
        float x1 = 0.f, y1 = 0.f, x2 = 0.f, y2 = 0.f, scv = -1.0f;
        if (tid < k) {
            unsigned idx = sel[base + tid];
            if (idx < (unsigned)TOTALN) {
                float o = obj_all[(size_t)img * TOTALN + idx];
                const float* dd = deltas + ((size_t)img * TOTALN + (size_t)idx) * 4;
                const float* aa = anchors + (size_t)idx * 4;
                float a0 = aa[0], a1 = aa[1], a2 = aa[2], a3 = aa[3];
                float w = a2 - a0, h = a3 - a1;
                float cx = a0 + 0.5f * w, cy = a1 + 0.5f * h;
                float dx = dd[0], dy = dd[1];
                float dw = fminf(dd[2], BBOX_CLIP), dh = fminf(dd[3], BBOX_CLIP);
                float pcx = dx * w + cx, pcy = dy * h + cy;
                float pw = expf(dw) * w, ph = expf(dh) * h;
                float bx1 = pcx - 0.5f * pw, by1 = pcy - 0.5f * ph;
                float bx2 = pcx + 0.5f * pw, by2 = pcy + 0.5f * ph;
                x1 = fminf(fmaxf(bx1, 0.f), IMGSZ);
                y1 = fminf(fmaxf(by1, 0.f), IMGSZ);
                x2 = fminf(fmaxf(bx2, 0.f), IMGSZ);
                y2 = fminf(fmaxf(by2, 0.f), IMGSZ);
                float wsz = x2 - x1, hsz = y2 - y1;
                if (wsz >= MINSZ && hsz >= MINSZ) scv = 1.0f / (1.0f + expf(-o));
            }
        }
        sx1[tid] = x1; sy1[tid] = y1; sx2[tid] = x2; sy2[tid] = y2;
        sar[tid] = (x2 - x1) * (y2 - y1);
        ssc[tid] = scv;
    }
    __syncthreads();

    // ---- mask rows: thread i computes words w >= i/64 (upper triangle) ----
    {
        const int i = tid;
        const float ix1 = sx1[i], iy1 = sy1[i], ix2 = sx2[i], iy2 = sy2[i], iar = sar[i];
        const int w0 = i >> 6;                    // wave-uniform
        for (int w = w0; w < 16; ++w) {
            unsigned long long bits = 0;
            const int j0 = w << 6;
#pragma unroll 8
            for (int jj = 0; jj < 64; ++jj) {
                const int j = j0 + jj;
                float ltx = fmaxf(ix1, sx1[j]), lty = fmaxf(iy1, sy1[j]);
                float rbx = fminf(ix2, sx2[j]), rby = fminf(iy2, sy2[j]);
                float wx = fmaxf(rbx - ltx, 0.f), wy = fmaxf(rby - lty, 0.f);
                float inter = wx * wy;
                float iou = inter / ((iar + sar[j]) - inter);
                if (iou > NMS_TH && j > i) bits |= (1ull << jj);
            }
            lmask[i][(w + i) & 15] = bits;
        }
    }
    __syncthreads();

    // ---- serial greedy scan on wave 0: uniform ffs chain, LDS mask reads ----
    if (tid < 64) {
        const int lane = tid, wsel = lane & 15;
        unsigned long long rem = 0;               // lane owns removal word (lane&15)
#pragma unroll
        for (int c = 0; c < 16; ++c) {
            unsigned long long wv = __ballot(ssc[(c << 6) + lane] <= 0.f);
            if (wsel == c) rem = wv;
        }
        int ns = 0;
        for (int g = 0; g < 16; ++g) {
            const int drow = (g << 6) + lane;
            unsigned long long dg = lmask[drow][(g + drow) & 15];  // diag word, lane=row-in-group
            unsigned long long s_cur = __shfl(rem, g);             // lane g owns word g
            unsigned long long alive = ~s_cur;
            while (alive) {
                int b = __ffsll((long long)alive) - 1;
                unsigned long long d = __shfl(dg, b);
                const int row = (g << 6) + b;
                rem |= lmask[row][(wsel + row) & 15];   // lazy cross-group update
                alive &= ~(d | (1ull << b));
                if (lane == 0) survL[ns] = (unsigned short)row;
                ++ns;
            }
        }
        if (lane == 0) s_ns = ns;
    }
    __syncthreads();

    // ---- survivor writeback (all waves) ----
    const int ns = s_ns;
    for (int s = tid; s < ns; s += 1024) {
        int r = survL[s];
        int o = base + s;
        svsc[o] = ssc[r];
        svbox[(size_t)o * 4 + 0] = sx1[r];
        svbox[(size_t)o * 4 + 1] = sy1[r];
        svbox[(size_t)o * 4 + 2] = sx2[r];
        svbox[(size_t)o * 4 + 3] = sy2[r];
    }
    if (tid == 0) svcnt[p] = ns;
}

// ---------------- merge 5 survivor lists per image by score (ties -> lower level) ----------------
__global__ __launch_bounds__(256) void merge_kernel(
    const float* __restrict__ svbox, const float* __restrict__ svsc,
    const int* __restrict__ svcnt, float* __restrict__ out) {
    __shared__ float sls[NLVL][CAP];
    __shared__ int scnt[NLVL];
    const int img = blockIdx.x, tid = threadIdx.x;
    if (tid < NLVL) scnt[tid] = svcnt[img * NLVL + tid];
    __syncthreads();
    for (int l = 0; l < NLVL; ++l) {
        int c = scnt[l];
        for (int i = tid; i < c; i += 256) sls[l][i] = svsc[(img * NLVL + l) * CAP + i];
    }
    __syncthreads();
    for (int l = 0; l < NLVL; ++l) {
        int c = scnt[l];
        for (int i = tid; i < c; i += 256) {
            float s = sls[l][i];
            int pos = i;
            for (int m = 0; m < NLVL; ++m) {
                if (m == l) continue;
                int n2 = scnt[m];
                int lo = 0, hi = n2;
                if (m < l) {
                    while (lo < hi) { int mid = (lo + hi) >> 1; if (sls[m][mid] >= s) lo = mid + 1; else hi = mid; }
                } else {
                    while (lo < hi) { int mid = (lo + hi) >> 1; if (sls[m][mid] > s)  lo = mid + 1; else hi = mid; }
                }
                pos += lo;
            }
            if (pos < POST_N) {
                int src = (img * NLVL + l) * CAP + i;
                float* o = out + ((size_t)img * POST_N + pos) * 5;
                o[0] = svbox[(size_t)src * 4 + 0];
                o[1] = svbox[(size_t)src * 4 + 1];
                o[2] = svbox[(size_t)src * 4 + 2];
                o[3] = svbox[(size_t)src * 4 + 3];
                o[4] = s;
            }
        }
    }
}

extern "C" void kernel_launch(void* const* d_in, const int* in_sizes, int n_in,
                              void* d_out, int out_size, void* d_ws, size_t ws_size,
                              hipStream_t stream) {
    const float* obj     = (const float*)d_in[0];
    const float* deltas  = (const float*)d_in[1];
    const float* anchors = (const float*)d_in[2];
    float* out = (float*)d_out;

    char* w = (char*)d_ws;
    size_t off = 0;
    auto alloc = [&](size_t bytes) -> void* {
        void* pp = w + off;
        off += (bytes + 511) & ~(size_t)511;
        return pp;
    };
    unsigned* ghist = (unsigned*)alloc((size_t)NPROB * HBINS * 4);
    unsigned* b1buf = (unsigned*)alloc((size_t)NPROB * 4);
    int*      ccnt  = (int*)alloc((size_t)NPROB * 4);
    unsigned long long* cand = (unsigned long long*)alloc((size_t)NPROB * CCAP * 8);
    unsigned* sel = (unsigned*)alloc((size_t)NPROB * CAP * 4);
    float* svbox = (float*)alloc((size_t)NPROB * CAP * 16);
    float* svsc  = (float*)alloc((size_t)NPROB * CAP * 4);
    int*   svcnt = (int*)alloc((size_t)NPROB * 4);
    if (off > ws_size) return;  // fail cleanly (output stays poisoned -> visible failure)

    hipMemsetAsync(ghist, 0, (size_t)NPROB * HBINS * 4, stream);
    hipMemsetAsync(ccnt, 0, (size_t)NPROB * 4, stream);
    hipMemsetAsync(d_out, 0, (size_t)out_size * sizeof(float), stream);

    hist_kernel<<<NBATCH * NCHUNK, 256, 0, stream>>>(obj, ghist);
    pick1_kernel<<<NPROB, 256, 0, stream>>>(ghist, b1buf);
    compact_kernel<<<NBATCH * NCHUNK, 256, 0, stream>>>(obj, b1buf, ccnt, cand);
    rank_kernel<<<NPROB * 16, 256, 0, stream>>>(cand, ccnt, sel);
    nms_fused_kernel<<<NPROB, 1024, 0, stream>>>(obj, deltas, anchors, sel,
                                                 svbox, svsc, svcnt);
    merge_kernel<<<NBATCH, 256, 0, stream>>>(svbox, svsc, svcnt, out);
}

// Round 8
// 328.476 us; speedup vs baseline: 1.1687x; 1.1687x over previous
//
#include <hip/hip_runtime.h>
#include <math.h>

#pragma clang fp contract(off)

#define NLVL 5
#define TOTALN 261888
#define NBATCH 16
#define CAP 1024
#define NPROB (NBATCH * NLVL)
#define POST_N 1000
#define NMS_TH 0.7f
#define MINSZ 1e-3f
#define IMGSZ 1024.0f
#define BBOX_CLIP 4.135166556742356f

#define HBINS 2048
#define CCAP 4096
#define NCHUNK 256   // ceil(261888/1024); level offsets are all multiples of 1024

__constant__ int c_loff[NLVL] = {0, 196608, 245760, 258048, 261120};
__constant__ int c_num[NLVL]  = {196608, 49152, 12288, 3072, 768};
__constant__ int c_k[NLVL]    = {1000, 1000, 1000, 1000, 768};

// (rg, wg) tile list for the upper-triangular mask: wg >= rg
__constant__ int c_rg[10] = {0,0,0,0,1,1,1,2,2,3};
__constant__ int c_wg[10] = {0,1,2,3,1,2,3,2,3,3};

__device__ __forceinline__ unsigned monokey(float f) {
    unsigned b = __float_as_uint(f);
    return (b & 0x80000000u) ? ~b : (b | 0x80000000u);
}

__device__ __forceinline__ int lvl_of_start(int start) {
    return (start >= 261120) ? 4 : (start >= 258048) ? 3 : (start >= 245760) ? 2
         : (start >= 196608) ? 1 : 0;
}

// ---------------- pass 1: per-chunk LDS histogram of top-11 key bits ----------------
__global__ __launch_bounds__(256) void hist_kernel(const float* __restrict__ obj_all,
                                                   unsigned* __restrict__ ghist) {
    __shared__ unsigned lh[HBINS];
    const int tid = threadIdx.x;
    const int chunk = blockIdx.x;
    const int img = chunk >> 8, c = chunk & 255;
    const int start = c << 10;
    const int lvl = lvl_of_start(start);
    const int nrem = min(1024, TOTALN - start);
    for (int i = tid; i < HBINS; i += 256) lh[i] = 0;
    __syncthreads();
    const float* o = obj_all + (size_t)img * TOTALN + start;
    for (int i = tid; i < nrem; i += 256) atomicAdd(&lh[monokey(o[i]) >> 21], 1u);
    __syncthreads();
    unsigned* gh = ghist + (size_t)(img * NLVL + lvl) * HBINS;
    for (int i = tid; i < HBINS; i += 256) {
        unsigned v = lh[i];
        if (v) atomicAdd(&gh[i], v);
    }
}

// ---------------- pick threshold bucket b1 per problem (suffix-sum of hist) ----------------
__global__ __launch_bounds__(256) void pick1_kernel(const unsigned* __restrict__ ghist,
                                                    unsigned* __restrict__ b1out) {
    __shared__ unsigned suf[HBINS];
    const int p = blockIdx.x, tid = threadIdx.x;
    const int k = c_k[p % NLVL];
    const unsigned* gh = ghist + (size_t)p * HBINS;
    for (int i = tid; i < HBINS; i += 256) suf[i] = gh[i];
    __syncthreads();
    for (int d = 1; d < HBINS; d <<= 1) {
        unsigned v[HBINS / 256];
#pragma unroll
        for (int r = 0; r < HBINS / 256; ++r) {
            int i = tid + r * 256;
            v[r] = suf[i] + ((i + d < HBINS) ? suf[i + d] : 0u);
        }
        __syncthreads();
#pragma unroll
        for (int r = 0; r < HBINS / 256; ++r) suf[tid + r * 256] = v[r];
        __syncthreads();
    }
#pragma unroll
    for (int r = 0; r < HBINS / 256; ++r) {
        int i = tid + r * 256;
        if (suf[i] >= (unsigned)k && (i == HBINS - 1 || suf[i + 1] < (unsigned)k))
            b1out[p] = (unsigned)i;
    }
}

// ---------------- pass 2: compact all keys >= (b1<<21) ----------------
__global__ __launch_bounds__(256) void compact_kernel(const float* __restrict__ obj_all,
                                                      const unsigned* __restrict__ b1in,
                                                      int* __restrict__ cnt,
                                                      unsigned long long* __restrict__ cand) {
    __shared__ unsigned long long lkey[1024];
    __shared__ int s_lc, s_base;
    const int tid = threadIdx.x;
    const int chunk = blockIdx.x;
    const int img = chunk >> 8, c = chunk & 255;
    const int start = c << 10;
    const int lvl = lvl_of_start(start);
    const int nrem = min(1024, TOTALN - start);
    const int p = img * NLVL + lvl;
    const unsigned thr = b1in[p] << 21;
    const int local0 = start - c_loff[lvl];
    if (tid == 0) s_lc = 0;
    __syncthreads();
    const float* o = obj_all + (size_t)img * TOTALN + start;
    for (int i = tid; i < nrem; i += 256) {
        unsigned key = monokey(o[i]);
        if (key >= thr) {
            int l = atomicAdd(&s_lc, 1);
            lkey[l] = (((unsigned long long)key) << 32) | (unsigned)(~(unsigned)(local0 + i));
        }
    }
    __syncthreads();
    if (tid == 0) s_base = atomicAdd(&cnt[p], s_lc);
    __syncthreads();
    const int lc = s_lc, base = s_base;
    unsigned long long* cd = cand + (size_t)p * CCAP;
    for (int i = tid; i < lc; i += 256) {
        int pos = base + i;
        if (pos < CCAP) cd[pos] = lkey[i];
    }
}

// ---------------- rank + decode fused: pos_i = #{j : key_j > key_i}; decode rank<k ----------------
// Keys distinct (index embedded) -> rank is an exact sort permutation; slots [0,k) all
// get written. csc default (memset 0) marks unwritten slots invalid (valid scores > 0).
__global__ __launch_bounds__(256) void rankdec_kernel(
    const unsigned long long* __restrict__ cand, const int* __restrict__ cnt,
    const float* __restrict__ obj_all, const float* __restrict__ deltas,
    const float* __restrict__ anchors,
    float4* __restrict__ cbox, float* __restrict__ csc) {
    __shared__ unsigned long long skey[CCAP];
    const int p = blockIdx.x >> 4;
    const int blk = blockIdx.x & 15;
    const int tid = threadIdx.x;
    const int lvl = p % NLVL, img = p / NLVL, k = c_k[lvl];
    int n = cnt[p]; if (n > CCAP) n = CCAP;
    const int i0 = blk << 8;
    if (i0 >= n) return;                       // block-uniform exit, no barrier crossed
    const unsigned long long* cd = cand + (size_t)p * CCAP;
    const int n8 = (n + 7) & ~7;
    for (int i = tid; i < n8; i += 256) skey[i] = (i < n) ? cd[i] : 0ull;
    __syncthreads();
    const int i = i0 + tid;
    const unsigned long long my = (i < n) ? skey[i] : ~0ull;  // sentinel -> rank 0, not emitted
    int rank = 0;
    for (int j = 0; j < n8; j += 8) {          // wave-uniform LDS broadcast reads
        unsigned long long k0 = skey[j + 0], k1 = skey[j + 1];
        unsigned long long k2 = skey[j + 2], k3 = skey[j + 3];
        unsigned long long k4 = skey[j + 4], k5 = skey[j + 5];
        unsigned long long k6 = skey[j + 6], k7 = skey[j + 7];
        rank += (int)(k0 > my) + (int)(k1 > my) + (int)(k2 > my) + (int)(k3 > my)
              + (int)(k4 > my) + (int)(k5 > my) + (int)(k6 > my) + (int)(k7 > my);
    }
    if (i < n && rank < k) {
        unsigned li = ~(unsigned)(my & 0xFFFFFFFFull);
        unsigned idx = (unsigned)c_loff[lvl] + li;
        float o = obj_all[(size_t)img * TOTALN + idx];
        const float* dd = deltas + ((size_t)img * TOTALN + (size_t)idx) * 4;
        const float* aa = anchors + (size_t)idx * 4;
        float a0 = aa[0], a1 = aa[1], a2 = aa[2], a3 = aa[3];
        float w = a2 - a0, h = a3 - a1;
        float cx = a0 + 0.5f * w, cy = a1 + 0.5f * h;
        float dx = dd[0], dy = dd[1];
        float dw = fminf(dd[2], BBOX_CLIP), dh = fminf(dd[3], BBOX_CLIP);
        float pcx = dx * w + cx, pcy = dy * h + cy;
        float pw = expf(dw) * w, ph = expf(dh) * h;
        float bx1 = pcx - 0.5f * pw, by1 = pcy - 0.5f * ph;
        float bx2 = pcx + 0.5f * pw, by2 = pcy + 0.5f * ph;
        float x1 = fminf(fmaxf(bx1, 0.f), IMGSZ);
        float y1 = fminf(fmaxf(by1, 0.f), IMGSZ);
        float x2 = fminf(fmaxf(bx2, 0.f), IMGSZ);
        float y2 = fminf(fmaxf(by2, 0.f), IMGSZ);
        float wsz = x2 - x1, hsz = y2 - y1;
        float scv = (wsz >= MINSZ && hsz >= MINSZ) ? 1.0f / (1.0f + expf(-o)) : 0.0f;
        cbox[(size_t)p * CAP + rank] = make_float4(x1, y1, x2, y2);
        csc[(size_t)p * CAP + rank] = scv;
    }
}

// ---------------- NMS phase 1: ballot-form pairwise mask (wave = one 64-col word) ------
// Block = (p, rg, wg), wg >= rg; wave v owns word w = wg*4+v, lane = column 64w+lane
// (column box in registers). Iterate rows of [rg*256, min(rg*256+256, 64(w+1))):
// 1 b128 + 1 b32 LDS broadcast per row, one ballot -> one 8B write from lane 0.
// Sub-diagonal words never written (consumed-only garbage, see scan).
__global__ __launch_bounds__(256) void mask_kernel(const float4* __restrict__ cbox,
                                                   unsigned long long* __restrict__ gmask) {
    __shared__ float4 srow[256];
    __shared__ float sarr[256];
    const int bid = blockIdx.x;
    const int p = bid / 10, pair = bid - p * 10;
    const int rg = c_rg[pair], wg = c_wg[pair];
    const int tid = threadIdx.x;
    const int base = p * CAP;

    {   // stage this tile's 256 row boxes
        float4 b = cbox[base + (rg << 8) + tid];
        srow[tid] = b;
        sarr[tid] = (b.z - b.x) * (b.w - b.y);
    }
    const int wid = tid >> 6, lane = tid & 63;
    const int w = (wg << 2) + wid;
    const float4 cb = cbox[base + (w << 6) + lane];   // column box, register-resident
    const float car = (cb.z - cb.x) * (cb.w - cb.y);
    __syncthreads();

    const int i0 = rg << 8;
    const int i1 = min(i0 + 256, (w + 1) << 6);
    for (int i = i0; i < i1; ++i) {
        const int ir = i - i0;
        float4 rb = srow[ir];
        float iar = sarr[ir];
        float ltx = fmaxf(rb.x, cb.x), lty = fmaxf(rb.y, cb.y);
        float rbx = fminf(rb.z, cb.z), rby = fminf(rb.w, cb.w);
        float wx = fmaxf(rbx - ltx, 0.f), wy = fmaxf(rby - lty, 0.f);
        float inter = wx * wy;
        float iou = inter / ((iar + car) - inter);    // IEEE div: must match reference rounding
        unsigned long long bits = __ballot(iou > NMS_TH);
        if ((i >> 6) == w) bits &= (0xFFFFFFFFFFFFFFFEull << (i & 63));  // keep j > i
        if (lane == 0) gmask[(((size_t)(base + i)) << 4) + w] = bits;
    }
}

// ---------------- NMS phase 2: bulk-load mask to LDS, then uniform ffs-chain scan ------
// 1024 threads: 16 waves copy the 128 KB mask (8 x dwordx4/thread, deep MLP -> BW-bound),
// then wave 0 runs the serial greedy chain against LDS (~40 cyc reads), all waves write back.
__global__ __launch_bounds__(1024) void scan_kernel(
    const unsigned long long* __restrict__ gmask,
    const float4* __restrict__ cbox, const float* __restrict__ csc,
    float* __restrict__ svbox, float* __restrict__ svsc, int* __restrict__ svcnt) {
    __shared__ unsigned long long lm[CAP * 16];
    __shared__ unsigned short survL[CAP];
    __shared__ int s_ns;
    const int p = blockIdx.x, tid = threadIdx.x;
    const int base = p * CAP;

    {   // bulk copy mask -> LDS (layout-preserving, coalesced dwordx4)
        const ulonglong2* g2 = (const ulonglong2*)(gmask + ((size_t)base << 4));
        ulonglong2* l2 = (ulonglong2*)lm;
#pragma unroll
        for (int c = 0; c < 8; ++c) l2[c * 1024 + tid] = g2[c * 1024 + tid];
    }
    __syncthreads();

    if (tid < 64) {
        const int lane = tid, wsel = lane & 15;
        unsigned long long rem = 0;               // lane owns removal word (lane&15)
#pragma unroll
        for (int c = 0; c < 16; ++c) {
            unsigned long long wv = __ballot(csc[base + (c << 6) + lane] <= 0.f);
            if (wsel == c) rem = wv;
        }
        int ns = 0;
        for (int g = 0; g < 16; ++g) {
            unsigned long long dg = lm[((((g << 6) + lane)) << 4) + g];  // diag word, lane=row
            unsigned long long cur = __shfl(rem, g);                     // lane g owns word g
            unsigned long long alive = ~cur;
            while (alive) {
                int b = __ffsll((long long)alive) - 1;                   // uniform
                unsigned long long d = __shfl(dg, b);
                const int row = (g << 6) + b;
                rem |= lm[(row << 4) + wsel];      // lazy cross-group update (off chain)
                alive &= ~(d | (1ull << b));
                if (lane == 0) survL[ns] = (unsigned short)row;
                ++ns;
            }
        }
        if (lane == 0) s_ns = ns;
    }
    __syncthreads();

    const int ns = s_ns;
    for (int s = tid; s < ns; s += 1024) {
        int r = survL[s];
        svsc[base + s] = csc[base + r];
        *(float4*)(svbox + ((size_t)(base + s)) * 4) = cbox[base + r];
    }
    if (tid == 0) svcnt[p] = ns;
}

// ---------------- merge 5 survivor lists per image by score (ties -> lower level) ----------------
__global__ __launch_bounds__(256) void merge_kernel(
    const float* __restrict__ svbox, const float* __restrict__ svsc,
    const int* __restrict__ svcnt, float* __restrict__ out) {
    __shared__ float sls[NLVL][CAP];
    __shared__ int scnt[NLVL];
    const int img = blockIdx.x, tid = threadIdx.x;
    if (tid < NLVL) scnt[tid] = svcnt[img * NLVL + tid];
    __syncthreads();
    for (int l = 0; l < NLVL; ++l) {
        int c = scnt[l];
        for (int i = tid; i < c; i += 256) sls[l][i] = svsc[(img * NLVL + l) * CAP + i];
    }
    __syncthreads();
    for (int l = 0; l < NLVL; ++l) {
        int c = scnt[l];
        for (int i = tid; i < c; i += 256) {
            float s = sls[l][i];
            int pos = i;
            for (int m = 0; m < NLVL; ++m) {
                if (m == l) continue;
                int n2 = scnt[m];
                int lo = 0, hi = n2;
                if (m < l) {
                    while (lo < hi) { int mid = (lo + hi) >> 1; if (sls[m][mid] >= s) lo = mid + 1; else hi = mid; }
                } else {
                    while (lo < hi) { int mid = (lo + hi) >> 1; if (sls[m][mid] > s)  lo = mid + 1; else hi = mid; }
                }
                pos += lo;
            }
            if (pos < POST_N) {
                int src = (img * NLVL + l) * CAP + i;
                float* o = out + ((size_t)img * POST_N + pos) * 5;
                o[0] = svbox[(size_t)src * 4 + 0];
                o[1] = svbox[(size_t)src * 4 + 1];
                o[2] = svbox[(size_t)src * 4 + 2];
                o[3] = svbox[(size_t)src * 4 + 3];
                o[4] = s;
            }
        }
    }
}

extern "C" void kernel_launch(void* const* d_in, const int* in_sizes, int n_in,
                              void* d_out, int out_size, void* d_ws, size_t ws_size,
                              hipStream_t stream) {
    const float* obj     = (const float*)d_in[0];
    const float* deltas  = (const float*)d_in[1];
    const float* anchors = (const float*)d_in[2];
    float* out = (float*)d_out;

    char* w = (char*)d_ws;
    size_t off = 0;
    auto alloc = [&](size_t bytes) -> void* {
        void* pp = w + off;
        off += (bytes + 511) & ~(size_t)511;
        return pp;
    };
    unsigned* ghist = (unsigned*)alloc((size_t)NPROB * HBINS * 4);
    unsigned* b1buf = (unsigned*)alloc((size_t)NPROB * 4);
    int*      ccnt  = (int*)alloc((size_t)NPROB * 4);
    unsigned long long* cand = (unsigned long long*)alloc((size_t)NPROB * CCAP * 8);
    float4*   cbox  = (float4*)alloc((size_t)NPROB * CAP * 16);
    float*    csc   = (float*)alloc((size_t)NPROB * CAP * 4);
    unsigned long long* gmask = (unsigned long long*)alloc((size_t)NPROB * CAP * 16 * 8);
    float* svbox = (float*)alloc((size_t)NPROB * CAP * 16);
    float* svsc  = (float*)alloc((size_t)NPROB * CAP * 4);
    int*   svcnt = (int*)alloc((size_t)NPROB * 4);
    if (off > ws_size) return;  // fail cleanly (output stays poisoned -> visible failure)

    hipMemsetAsync(ghist, 0, (size_t)NPROB * HBINS * 4, stream);
    hipMemsetAsync(ccnt, 0, (size_t)NPROB * 4, stream);
    hipMemsetAsync(csc, 0, (size_t)NPROB * CAP * 4, stream);
    hipMemsetAsync(d_out, 0, (size_t)out_size * sizeof(float), stream);

    hist_kernel<<<NBATCH * NCHUNK, 256, 0, stream>>>(obj, ghist);
    pick1_kernel<<<NPROB, 256, 0, stream>>>(ghist, b1buf);
    compact_kernel<<<NBATCH * NCHUNK, 256, 0, stream>>>(obj, b1buf, ccnt, cand);
    rankdec_kernel<<<NPROB * 16, 256, 0, stream>>>(cand, ccnt, obj, deltas, anchors,
                                                   cbox, csc);
    mask_kernel<<<NPROB * 10, 256, 0, stream>>>(cbox, gmask);
    scan_kernel<<<NPROB, 1024, 0, stream>>>(gmask, cbox, csc, svbox, svsc, svcnt);
    merge_kernel<<<NBATCH, 256, 0, stream>>>(svbox, svsc, svcnt, out);
}

// Round 9
// 318.023 us; speedup vs baseline: 1.2071x; 1.0329x over previous
//
#include <hip/hip_runtime.h>
#include <math.h>

#pragma clang fp contract(off)

#define NLVL 5
#define TOTALN 261888
#define NBATCH 16
#define CAP 1024
#define NPROB (NBATCH * NLVL)
#define POST_N 1000
#define NMS_TH 0.7f
#define MINSZ 1e-3f
#define IMGSZ 1024.0f
#define BBOX_CLIP 4.135166556742356f

#define HBINS 2048
#define CCAP 4096
#define NCHUNK 256   // ceil(261888/1024); level offsets are all multiples of 1024

__constant__ int c_loff[NLVL] = {0, 196608, 245760, 258048, 261120};
__constant__ int c_num[NLVL]  = {196608, 49152, 12288, 3072, 768};
__constant__ int c_k[NLVL]    = {1000, 1000, 1000, 1000, 768};

// (rg, wg) tile list for the upper-triangular mask: wg >= rg
__constant__ int c_rg[10] = {0,0,0,0,1,1,1,2,2,3};
__constant__ int c_wg[10] = {0,1,2,3,1,2,3,2,3,3};

__device__ __forceinline__ unsigned monokey(float f) {
    unsigned b = __float_as_uint(f);
    return (b & 0x80000000u) ? ~b : (b | 0x80000000u);
}

__device__ __forceinline__ int lvl_of_start(int start) {
    return (start >= 261120) ? 4 : (start >= 258048) ? 3 : (start >= 245760) ? 2
         : (start >= 196608) ? 1 : 0;
}

// ---------------- pass 1: per-chunk LDS histogram of top-11 key bits ----------------
__global__ __launch_bounds__(256) void hist_kernel(const float* __restrict__ obj_all,
                                                   unsigned* __restrict__ ghist) {
    __shared__ unsigned lh[HBINS];
    const int tid = threadIdx.x;
    const int chunk = blockIdx.x;
    const int img = chunk >> 8, c = chunk & 255;
    const int start = c << 10;
    const int lvl = lvl_of_start(start);
    const int nrem = min(1024, TOTALN - start);
    for (int i = tid; i < HBINS; i += 256) lh[i] = 0;
    __syncthreads();
    const float* o = obj_all + (size_t)img * TOTALN + start;
    for (int i = tid; i < nrem; i += 256) atomicAdd(&lh[monokey(o[i]) >> 21], 1u);
    __syncthreads();
    unsigned* gh = ghist + (size_t)(img * NLVL + lvl) * HBINS;
    for (int i = tid; i < HBINS; i += 256) {
        unsigned v = lh[i];
        if (v) atomicAdd(&gh[i], v);
    }
}

// ---------------- pick threshold bucket b1 per problem (suffix-sum of hist) ----------------
__global__ __launch_bounds__(256) void pick1_kernel(const unsigned* __restrict__ ghist,
                                                    unsigned* __restrict__ b1out) {
    __shared__ unsigned suf[HBINS];
    const int p = blockIdx.x, tid = threadIdx.x;
    const int k = c_k[p % NLVL];
    const unsigned* gh = ghist + (size_t)p * HBINS;
    for (int i = tid; i < HBINS; i += 256) suf[i] = gh[i];
    __syncthreads();
    for (int d = 1; d < HBINS; d <<= 1) {
        unsigned v[HBINS / 256];
#pragma unroll
        for (int r = 0; r < HBINS / 256; ++r) {
            int i = tid + r * 256;
            v[r] = suf[i] + ((i + d < HBINS) ? suf[i + d] : 0u);
        }
        __syncthreads();
#pragma unroll
        for (int r = 0; r < HBINS / 256; ++r) suf[tid + r * 256] = v[r];
        __syncthreads();
    }
#pragma unroll
    for (int r = 0; r < HBINS / 256; ++r) {
        int i = tid + r * 256;
        if (suf[i] >= (unsigned)k && (i == HBINS - 1 || suf[i + 1] < (unsigned)k))
            b1out[p] = (unsigned)i;
    }
}

// ---------------- pass 2: compact all keys >= (b1<<21) ----------------
__global__ __launch_bounds__(256) void compact_kernel(const float* __restrict__ obj_all,
                                                      const unsigned* __restrict__ b1in,
                                                      int* __restrict__ cnt,
                                                      unsigned long long* __restrict__ cand) {
    __shared__ unsigned long long lkey[1024];
    __shared__ int s_lc, s_base;
    const int tid = threadIdx.x;
    const int chunk = blockIdx.x;
    const int img = chunk >> 8, c = chunk & 255;
    const int start = c << 10;
    const int lvl = lvl_of_start(start);
    const int nrem = min(1024, TOTALN - start);
    const int p = img * NLVL + lvl;
    const unsigned thr = b1in[p] << 21;
    const int local0 = start - c_loff[lvl];
    if (tid == 0) s_lc = 0;
    __syncthreads();
    const float* o = obj_all + (size_t)img * TOTALN + start;
    for (int i = tid; i < nrem; i += 256) {
        unsigned key = monokey(o[i]);
        if (key >= thr) {
            int l = atomicAdd(&s_lc, 1);
            lkey[l] = (((unsigned long long)key) << 32) | (unsigned)(~(unsigned)(local0 + i));
        }
    }
    __syncthreads();
    if (tid == 0) s_base = atomicAdd(&cnt[p], s_lc);
    __syncthreads();
    const int lc = s_lc, base = s_base;
    unsigned long long* cd = cand + (size_t)p * CCAP;
    for (int i = tid; i < lc; i += 256) {
        int pos = base + i;
        if (pos < CCAP) cd[pos] = lkey[i];
    }
}

// ---------------- rank + decode fused: pos_i = #{j : key_j > key_i}; decode rank<k ----------------
__global__ __launch_bounds__(256) void rankdec_kernel(
    const unsigned long long* __restrict__ cand, const int* __restrict__ cnt,
    const float* __restrict__ obj_all, const float* __restrict__ deltas,
    const float* __restrict__ anchors,
    float4* __restrict__ cbox, float* __restrict__ csc) {
    __shared__ unsigned long long skey[CCAP];
    const int p = blockIdx.x >> 4;
    const int blk = blockIdx.x & 15;
    const int tid = threadIdx.x;
    const int lvl = p % NLVL, img = p / NLVL, k = c_k[lvl];
    int n = cnt[p]; if (n > CCAP) n = CCAP;
    const int i0 = blk << 8;
    if (i0 >= n) return;                       // block-uniform exit, no barrier crossed
    const unsigned long long* cd = cand + (size_t)p * CCAP;
    const int n8 = (n + 7) & ~7;
    for (int i = tid; i < n8; i += 256) skey[i] = (i < n) ? cd[i] : 0ull;
    __syncthreads();
    const int i = i0 + tid;
    const unsigned long long my = (i < n) ? skey[i] : ~0ull;  // sentinel -> rank 0, not emitted
    int rank = 0;
    for (int j = 0; j < n8; j += 8) {          // wave-uniform LDS broadcast reads
        unsigned long long k0 = skey[j + 0], k1 = skey[j + 1];
        unsigned long long k2 = skey[j + 2], k3 = skey[j + 3];
        unsigned long long k4 = skey[j + 4], k5 = skey[j + 5];
        unsigned long long k6 = skey[j + 6], k7 = skey[j + 7];
        rank += (int)(k0 > my) + (int)(k1 > my) + (int)(k2 > my) + (int)(k3 > my)
              + (int)(k4 > my) + (int)(k5 > my) + (int)(k6 > my) + (int)(k7 > my);
    }
    if (i < n && rank < k) {
        unsigned li = ~(unsigned)(my & 0xFFFFFFFFull);
        unsigned idx = (unsigned)c_loff[lvl] + li;
        float o = obj_all[(size_t)img * TOTALN + idx];
        const float* dd = deltas + ((size_t)img * TOTALN + (size_t)idx) * 4;
        const float* aa = anchors + (size_t)idx * 4;
        float a0 = aa[0], a1 = aa[1], a2 = aa[2], a3 = aa[3];
        float w = a2 - a0, h = a3 - a1;
        float cx = a0 + 0.5f * w, cy = a1 + 0.5f * h;
        float dx = dd[0], dy = dd[1];
        float dw = fminf(dd[2], BBOX_CLIP), dh = fminf(dd[3], BBOX_CLIP);
        float pcx = dx * w + cx, pcy = dy * h + cy;
        float pw = expf(dw) * w, ph = expf(dh) * h;
        float bx1 = pcx - 0.5f * pw, by1 = pcy - 0.5f * ph;
        float bx2 = pcx + 0.5f * pw, by2 = pcy + 0.5f * ph;
        float x1 = fminf(fmaxf(bx1, 0.f), IMGSZ);
        float y1 = fminf(fmaxf(by1, 0.f), IMGSZ);
        float x2 = fminf(fmaxf(bx2, 0.f), IMGSZ);
        float y2 = fminf(fmaxf(by2, 0.f), IMGSZ);
        float wsz = x2 - x1, hsz = y2 - y1;
        float scv = (wsz >= MINSZ && hsz >= MINSZ) ? 1.0f / (1.0f + expf(-o)) : 0.0f;
        cbox[(size_t)p * CAP + rank] = make_float4(x1, y1, x2, y2);
        csc[(size_t)p * CAP + rank] = scv;
    }
}

// ---------------- NMS phase 1: ballot-form pairwise mask + transposed diagonal ----------
// Block = (p, rg, wg), wg >= rg; wave v owns word w = wg*4+v, lane = column 64w+lane.
// gmask[(base+i)*16+w] bit j: row i suppresses col 64w+j (j>i).  Diagonal tiles also
// emit tdiag[p][w][lane] bit r: row 64w+r suppresses col 64w+lane  (per-lane accumulate).
// Sub-diagonal words never written (consumed-only garbage; scan reads only w >= row/64).
__global__ __launch_bounds__(256) void mask_kernel(const float4* __restrict__ cbox,
                                                   unsigned long long* __restrict__ gmask,
                                                   unsigned long long* __restrict__ tdiag) {
    __shared__ float4 srow[256];
    __shared__ float sarr[256];
    const int bid = blockIdx.x;
    const int p = bid / 10, pair = bid - p * 10;
    const int rg = c_rg[pair], wg = c_wg[pair];
    const int tid = threadIdx.x;
    const int base = p * CAP;

    {   // stage this tile's 256 row boxes
        float4 b = cbox[base + (rg << 8) + tid];
        srow[tid] = b;
        sarr[tid] = (b.z - b.x) * (b.w - b.y);
    }
    const int wid = tid >> 6, lane = tid & 63;
    const int w = (wg << 2) + wid;
    const int jg = (w << 6) + lane;                   // this lane's global column
    const float4 cb = cbox[base + jg];                // column box, register-resident
    const float car = (cb.z - cb.x) * (cb.w - cb.y);
    __syncthreads();

    const int i0 = rg << 8;
    const int i1 = min(i0 + 256, (w + 1) << 6);
    unsigned long long tbits = 0;
    for (int i = i0; i < i1; ++i) {
        const int ir = i - i0;
        float4 rb = srow[ir];
        float iar = sarr[ir];
        float ltx = fmaxf(rb.x, cb.x), lty = fmaxf(rb.y, cb.y);
        float rbx = fminf(rb.z, cb.z), rby = fminf(rb.w, cb.w);
        float wx = fmaxf(rbx - ltx, 0.f), wy = fmaxf(rby - lty, 0.f);
        float inter = wx * wy;
        float iou = inter / ((iar + car) - inter);    // IEEE div: must match reference rounding
        bool sup = iou > NMS_TH;
        unsigned long long bits = __ballot(sup);
        if ((i >> 6) == w) {
            bits &= (0xFFFFFFFFFFFFFFFEull << (i & 63));  // keep j > i
            if (sup && jg > i) tbits |= (1ull << (i & 63));
        }
        if (lane == 0) gmask[(((size_t)(base + i)) << 4) + w] = bits;
    }
    if (wg == rg) tdiag[((size_t)p << 10) + (w << 6) + lane] = tbits;
}

// ---------------- NMS phase 2: bulk mask->LDS + register-chain greedy scan ------------
// 1024 threads copy the 128 KB mask; wave 0 then scans. Per-accept chain is pure
// SALU/VALU: ffs -> (tg>>b)&1 -> ballot -> alive update (no LDS/shuffle on chain).
// Cross-group suppression is recomputed per group start from survL (independent LDS
// loads, 4-way unrolled, then 6-step shfl_xor OR-reduce).
__global__ __launch_bounds__(1024) void scan_kernel(
    const unsigned long long* __restrict__ gmask,
    const unsigned long long* __restrict__ tdiag,
    const float4* __restrict__ cbox, const float* __restrict__ csc,
    float* __restrict__ svbox, float* __restrict__ svsc, int* __restrict__ svcnt) {
    __shared__ unsigned long long lm[CAP * 16];
    __shared__ float ssc[CAP];
    __shared__ unsigned short survL[CAP];
    __shared__ int s_ns;
    const int p = blockIdx.x, tid = threadIdx.x;
    const int base = p * CAP;

    {   // bulk copy mask -> LDS (layout-preserving, coalesced dwordx4)
        const ulonglong2* g2 = (const ulonglong2*)(gmask + ((size_t)base << 4));
        ulonglong2* l2 = (ulonglong2*)lm;
#pragma unroll
        for (int c = 0; c < 8; ++c) l2[c * 1024 + tid] = g2[c * 1024 + tid];
        ssc[tid] = csc[base + tid];
    }
    __syncthreads();

    if (tid < 64) {
        const int lane = tid;
        const unsigned long long* td = tdiag + ((size_t)p << 10);
        unsigned long long tg = td[lane];          // group 0 transposed diagonal
        int ns = 0;
        for (int g = 0; g < 16; ++g) {
            unsigned long long tgn = (g < 15) ? td[((g + 1) << 6) + lane] : 0ull;
            unsigned long long wv = __ballot(ssc[(g << 6) + lane] <= 0.f);
            // cross-group suppression: OR word g over all prior accepts
            unsigned long long a0 = 0, a1 = 0, a2 = 0, a3 = 0;
            int j = lane;
            for (; j + 192 < ns; j += 256) {
                int r0 = survL[j], r1 = survL[j + 64];
                int r2 = survL[j + 128], r3 = survL[j + 192];
                a0 |= lm[(r0 << 4) + g];
                a1 |= lm[(r1 << 4) + g];
                a2 |= lm[(r2 << 4) + g];
                a3 |= lm[(r3 << 4) + g];
            }
            for (; j < ns; j += 64) a0 |= lm[(((int)survL[j]) << 4) + g];
            unsigned long long accw = (a0 | a1) | (a2 | a3);
#pragma unroll
            for (int d2 = 1; d2 < 64; d2 <<= 1)
                accw |= (unsigned long long)__shfl_xor((unsigned long long)accw, d2);

            unsigned long long alive = ~(wv | accw);
            while (alive) {
                int b = __ffsll((long long)alive) - 1;             // uniform
                bool kill = ((tg >> b) & 1ull) != 0ull;            // per-lane register bit
                unsigned long long ball = __ballot(kill);
                if (lane == 0) survL[ns] = (unsigned short)((g << 6) + b);
                ++ns;
                alive &= ~(ball | (1ull << b));
            }
            tg = tgn;
        }
        if (lane == 0) s_ns = ns;
    }
    __syncthreads();

    const int ns = s_ns;
    for (int s = tid; s < ns; s += 1024) {
        int r = survL[s];
        svsc[base + s] = ssc[r];
        *(float4*)(svbox + ((size_t)(base + s)) * 4) = cbox[base + r];
    }
    if (tid == 0) svcnt[p] = ns;
}

// ---------------- merge 5 survivor lists per image by score (ties -> lower level) ----------------
__global__ __launch_bounds__(256) void merge_kernel(
    const float* __restrict__ svbox, const float* __restrict__ svsc,
    const int* __restrict__ svcnt, float* __restrict__ out) {
    __shared__ float sls[NLVL][CAP];
    __shared__ int scnt[NLVL];
    const int img = blockIdx.x, tid = threadIdx.x;
    if (tid < NLVL) scnt[tid] = svcnt[img * NLVL + tid];
    __syncthreads();
    for (int l = 0; l < NLVL; ++l) {
        int c = scnt[l];
        for (int i = tid; i < c; i += 256) sls[l][i] = svsc[(img * NLVL + l) * CAP + i];
    }
    __syncthreads();
    for (int l = 0; l < NLVL; ++l) {
        int c = scnt[l];
        for (int i = tid; i < c; i += 256) {
            float s = sls[l][i];
            int pos = i;
            for (int m = 0; m < NLVL; ++m) {
                if (m == l) continue;
                int n2 = scnt[m];
                int lo = 0, hi = n2;
                if (m < l) {
                    while (lo < hi) { int mid = (lo + hi) >> 1; if (sls[m][mid] >= s) lo = mid + 1; else hi = mid; }
                } else {
                    while (lo < hi) { int mid = (lo + hi) >> 1; if (sls[m][mid] > s)  lo = mid + 1; else hi = mid; }
                }
                pos += lo;
            }
            if (pos < POST_N) {
                int src = (img * NLVL + l) * CAP + i;
                float* o = out + ((size_t)img * POST_N + pos) * 5;
                o[0] = svbox[(size_t)src * 4 + 0];
                o[1] = svbox[(size_t)src * 4 + 1];
                o[2] = svbox[(size_t)src * 4 + 2];
                o[3] = svbox[(size_t)src * 4 + 3];
                o[4] = s;
            }
        }
    }
}

extern "C" void kernel_launch(void* const* d_in, const int* in_sizes, int n_in,
                              void* d_out, int out_size, void* d_ws, size_t ws_size,
                              hipStream_t stream) {
    const float* obj     = (const float*)d_in[0];
    const float* deltas  = (const float*)d_in[1];
    const float* anchors = (const float*)d_in[2];
    float* out = (float*)d_out;

    char* w = (char*)d_ws;
    size_t off = 0;
    auto alloc = [&](size_t bytes) -> void* {
        void* pp = w + off;
        off += (bytes + 511) & ~(size_t)511;
        return pp;
    };
    unsigned* ghist = (unsigned*)alloc((size_t)NPROB * HBINS * 4);
    unsigned* b1buf = (unsigned*)alloc((size_t)NPROB * 4);
    int*      ccnt  = (int*)alloc((size_t)NPROB * 4);
    unsigned long long* cand = (unsigned long long*)alloc((size_t)NPROB * CCAP * 8);
    float4*   cbox  = (float4*)alloc((size_t)NPROB * CAP * 16);
    float*    csc   = (float*)alloc((size_t)NPROB * CAP * 4);
    unsigned long long* gmask = (unsigned long long*)alloc((size_t)NPROB * CAP * 16 * 8);
    unsigned long long* tdiag = (unsigned long long*)alloc((size_t)NPROB * CAP * 8);
    float* svbox = (float*)alloc((size_t)NPROB * CAP * 16);
    float* svsc  = (float*)alloc((size_t)NPROB * CAP * 4);
    int*   svcnt = (int*)alloc((size_t)NPROB * 4);
    if (off > ws_size) return;  // fail cleanly (output stays poisoned -> visible failure)

    hipMemsetAsync(ghist, 0, (size_t)NPROB * HBINS * 4, stream);
    hipMemsetAsync(ccnt, 0, (size_t)NPROB * 4, stream);
    hipMemsetAsync(csc, 0, (size_t)NPROB * CAP * 4, stream);
    hipMemsetAsync(d_out, 0, (size_t)out_size * sizeof(float), stream);

    hist_kernel<<<NBATCH * NCHUNK, 256, 0, stream>>>(obj, ghist);
    pick1_kernel<<<NPROB, 256, 0, stream>>>(ghist, b1buf);
    compact_kernel<<<NBATCH * NCHUNK, 256, 0, stream>>>(obj, b1buf, ccnt, cand);
    rankdec_kernel<<<NPROB * 16, 256, 0, stream>>>(cand, ccnt, obj, deltas, anchors,
                                                   cbox, csc);
    mask_kernel<<<NPROB * 10, 256, 0, stream>>>(cbox, gmask, tdiag);
    scan_kernel<<<NPROB, 1024, 0, stream>>>(gmask, tdiag, cbox, csc, svbox, svsc, svcnt);
    merge_kernel<<<NBATCH, 256, 0, stream>>>(svbox, svsc, svcnt, out);
}

// Round 10
// 249.404 us; speedup vs baseline: 1.5392x; 1.2751x over previous
//
#include <hip/hip_runtime.h>
#include <math.h>

#pragma clang fp contract(off)

#define NLVL 5
#define TOTALN 261888
#define NBATCH 16
#define CAP 1024
#define NPROB (NBATCH * NLVL)
#define POST_N 1000
#define NMS_TH 0.7f
#define MINSZ 1e-3f
#define IMGSZ 1024.0f
#define BBOX_CLIP 4.135166556742356f

#define HBINS 2048
#define CCAP 4096
#define NCHUNK 256   // ceil(261888/1024); level offsets are all multiples of 1024
#define LMS 17       // LDS mask row stride in u64 words (bank-spread for row gathers)

__constant__ int c_loff[NLVL] = {0, 196608, 245760, 258048, 261120};
__constant__ int c_num[NLVL]  = {196608, 49152, 12288, 3072, 768};
__constant__ int c_k[NLVL]    = {1000, 1000, 1000, 1000, 768};

// (rg, wg) tile list for the upper-triangular mask: wg >= rg
__constant__ int c_rg[10] = {0,0,0,0,1,1,1,2,2,3};
__constant__ int c_wg[10] = {0,1,2,3,1,2,3,2,3,3};

__device__ __forceinline__ unsigned monokey(float f) {
    unsigned b = __float_as_uint(f);
    return (b & 0x80000000u) ? ~b : (b | 0x80000000u);
}

__device__ __forceinline__ int lvl_of_start(int start) {
    return (start >= 261120) ? 4 : (start >= 258048) ? 3 : (start >= 245760) ? 2
         : (start >= 196608) ? 1 : 0;
}

// ---------------- pass 1: per-chunk LDS histogram of top-11 key bits ----------------
__global__ __launch_bounds__(256) void hist_kernel(const float* __restrict__ obj_all,
                                                   unsigned* __restrict__ ghist) {
    __shared__ unsigned lh[HBINS];
    const int tid = threadIdx.x;
    const int chunk = blockIdx.x;
    const int img = chunk >> 8, c = chunk & 255;
    const int start = c << 10;
    const int lvl = lvl_of_start(start);
    const int nrem = min(1024, TOTALN - start);
    for (int i = tid; i < HBINS; i += 256) lh[i] = 0;
    __syncthreads();
    const float* o = obj_all + (size_t)img * TOTALN + start;
    for (int i = tid; i < nrem; i += 256) atomicAdd(&lh[monokey(o[i]) >> 21], 1u);
    __syncthreads();
    unsigned* gh = ghist + (size_t)(img * NLVL + lvl) * HBINS;
    for (int i = tid; i < HBINS; i += 256) {
        unsigned v = lh[i];
        if (v) atomicAdd(&gh[i], v);
    }
}

// ---------------- pick threshold bucket b1 per problem (suffix-sum of hist) ----------------
__global__ __launch_bounds__(256) void pick1_kernel(const unsigned* __restrict__ ghist,
                                                    unsigned* __restrict__ b1out) {
    __shared__ unsigned suf[HBINS];
    const int p = blockIdx.x, tid = threadIdx.x;
    const int k = c_k[p % NLVL];
    const unsigned* gh = ghist + (size_t)p * HBINS;
    for (int i = tid; i < HBINS; i += 256) suf[i] = gh[i];
    __syncthreads();
    for (int d = 1; d < HBINS; d <<= 1) {
        unsigned v[HBINS / 256];
#pragma unroll
        for (int r = 0; r < HBINS / 256; ++r) {
            int i = tid + r * 256;
            v[r] = suf[i] + ((i + d < HBINS) ? suf[i + d] : 0u);
        }
        __syncthreads();
#pragma unroll
        for (int r = 0; r < HBINS / 256; ++r) suf[tid + r * 256] = v[r];
        __syncthreads();
    }
#pragma unroll
    for (int r = 0; r < HBINS / 256; ++r) {
        int i = tid + r * 256;
        if (suf[i] >= (unsigned)k && (i == HBINS - 1 || suf[i + 1] < (unsigned)k))
            b1out[p] = (unsigned)i;
    }
}

// ---------------- pass 2: compact all keys >= (b1<<21) ----------------
__global__ __launch_bounds__(256) void compact_kernel(const float* __restrict__ obj_all,
                                                      const unsigned* __restrict__ b1in,
                                                      int* __restrict__ cnt,
                                                      unsigned long long* __restrict__ cand) {
    __shared__ unsigned long long lkey[1024];
    __shared__ int s_lc, s_base;
    const int tid = threadIdx.x;
    const int chunk = blockIdx.x;
    const int img = chunk >> 8, c = chunk & 255;
    const int start = c << 10;
    const int lvl = lvl_of_start(start);
    const int nrem = min(1024, TOTALN - start);
    const int p = img * NLVL + lvl;
    const unsigned thr = b1in[p] << 21;
    const int local0 = start - c_loff[lvl];
    if (tid == 0) s_lc = 0;
    __syncthreads();
    const float* o = obj_all + (size_t)img * TOTALN + start;
    for (int i = tid; i < nrem; i += 256) {
        unsigned key = monokey(o[i]);
        if (key >= thr) {
            int l = atomicAdd(&s_lc, 1);
            lkey[l] = (((unsigned long long)key) << 32) | (unsigned)(~(unsigned)(local0 + i));
        }
    }
    __syncthreads();
    if (tid == 0) s_base = atomicAdd(&cnt[p], s_lc);
    __syncthreads();
    const int lc = s_lc, base = s_base;
    unsigned long long* cd = cand + (size_t)p * CCAP;
    for (int i = tid; i < lc; i += 256) {
        int pos = base + i;
        if (pos < CCAP) cd[pos] = lkey[i];
    }
}

// ---------------- rank + decode fused: pos_i = #{j : key_j > key_i}; decode rank<k ----------------
__global__ __launch_bounds__(256) void rankdec_kernel(
    const unsigned long long* __restrict__ cand, const int* __restrict__ cnt,
    const float* __restrict__ obj_all, const float* __restrict__ deltas,
    const float* __restrict__ anchors,
    float4* __restrict__ cbox, float* __restrict__ csc) {
    __shared__ unsigned long long skey[CCAP];
    const int p = blockIdx.x >> 4;
    const int blk = blockIdx.x & 15;
    const int tid = threadIdx.x;
    const int lvl = p % NLVL, img = p / NLVL, k = c_k[lvl];
    int n = cnt[p]; if (n > CCAP) n = CCAP;
    const int i0 = blk << 8;
    if (i0 >= n) return;                       // block-uniform exit, no barrier crossed
    const unsigned long long* cd = cand + (size_t)p * CCAP;
    const int n8 = (n + 7) & ~7;
    for (int i = tid; i < n8; i += 256) skey[i] = (i < n) ? cd[i] : 0ull;
    __syncthreads();
    const int i = i0 + tid;
    const unsigned long long my = (i < n) ? skey[i] : ~0ull;  // sentinel -> rank 0, not emitted
    int rank = 0;
    for (int j = 0; j < n8; j += 8) {          // wave-uniform LDS broadcast reads
        unsigned long long k0 = skey[j + 0], k1 = skey[j + 1];
        unsigned long long k2 = skey[j + 2], k3 = skey[j + 3];
        unsigned long long k4 = skey[j + 4], k5 = skey[j + 5];
        unsigned long long k6 = skey[j + 6], k7 = skey[j + 7];
        rank += (int)(k0 > my) + (int)(k1 > my) + (int)(k2 > my) + (int)(k3 > my)
              + (int)(k4 > my) + (int)(k5 > my) + (int)(k6 > my) + (int)(k7 > my);
    }
    if (i < n && rank < k) {
        unsigned li = ~(unsigned)(my & 0xFFFFFFFFull);
        unsigned idx = (unsigned)c_loff[lvl] + li;
        float o = obj_all[(size_t)img * TOTALN + idx];
        const float* dd = deltas + ((size_t)img * TOTALN + (size_t)idx) * 4;
        const float* aa = anchors + (size_t)idx * 4;
        float a0 = aa[0], a1 = aa[1], a2 = aa[2], a3 = aa[3];
        float w = a2 - a0, h = a3 - a1;
        float cx = a0 + 0.5f * w, cy = a1 + 0.5f * h;
        float dx = dd[0], dy = dd[1];
        float dw = fminf(dd[2], BBOX_CLIP), dh = fminf(dd[3], BBOX_CLIP);
        float pcx = dx * w + cx, pcy = dy * h + cy;
        float pw = expf(dw) * w, ph = expf(dh) * h;
        float bx1 = pcx - 0.5f * pw, by1 = pcy - 0.5f * ph;
        float bx2 = pcx + 0.5f * pw, by2 = pcy + 0.5f * ph;
        float x1 = fminf(fmaxf(bx1, 0.f), IMGSZ);
        float y1 = fminf(fmaxf(by1, 0.f), IMGSZ);
        float x2 = fminf(fmaxf(bx2, 0.f), IMGSZ);
        float y2 = fminf(fmaxf(by2, 0.f), IMGSZ);
        float wsz = x2 - x1, hsz = y2 - y1;
        float scv = (wsz >= MINSZ && hsz >= MINSZ) ? 1.0f / (1.0f + expf(-o)) : 0.0f;
        cbox[(size_t)p * CAP + rank] = make_float4(x1, y1, x2, y2);
        csc[(size_t)p * CAP + rank] = scv;
    }
}

// ---------------- NMS phase 1: ballot-form pairwise mask + transposed diagonal ----------
// gmask[(base+i)*16+w] bit j: row i suppresses col 64w+j (j>i).  Diagonal tiles also
// emit tdiag[p][w][lane] bit r: row 64w+r suppresses col 64w+lane (strictly r < col).
// Sub-diagonal words never written (consumed-only garbage; scan reads only w > row/64).
__global__ __launch_bounds__(256) void mask_kernel(const float4* __restrict__ cbox,
                                                   unsigned long long* __restrict__ gmask,
                                                   unsigned long long* __restrict__ tdiag) {
    __shared__ float4 srow[256];
    __shared__ float sarr[256];
    const int bid = blockIdx.x;
    const int p = bid / 10, pair = bid - p * 10;
    const int rg = c_rg[pair], wg = c_wg[pair];
    const int tid = threadIdx.x;
    const int base = p * CAP;

    {   // stage this tile's 256 row boxes
        float4 b = cbox[base + (rg << 8) + tid];
        srow[tid] = b;
        sarr[tid] = (b.z - b.x) * (b.w - b.y);
    }
    const int wid = tid >> 6, lane = tid & 63;
    const int w = (wg << 2) + wid;
    const int jg = (w << 6) + lane;                   // this lane's global column
    const float4 cb = cbox[base + jg];                // column box, register-resident
    const float car = (cb.z - cb.x) * (cb.w - cb.y);
    __syncthreads();

    const int i0 = rg << 8;
    const int i1 = min(i0 + 256, (w + 1) << 6);
    unsigned long long tbits = 0;
    for (int i = i0; i < i1; ++i) {
        const int ir = i - i0;
        float4 rb = srow[ir];
        float iar = sarr[ir];
        float ltx = fmaxf(rb.x, cb.x), lty = fmaxf(rb.y, cb.y);
        float rbx = fminf(rb.z, cb.z), rby = fminf(rb.w, cb.w);
        float wx = fmaxf(rbx - ltx, 0.f), wy = fmaxf(rby - lty, 0.f);
        float inter = wx * wy;
        float iou = inter / ((iar + car) - inter);    // IEEE div: must match reference rounding
        bool sup = iou > NMS_TH;
        unsigned long long bits = __ballot(sup);
        if ((i >> 6) == w) {
            bits &= (0xFFFFFFFFFFFFFFFEull << (i & 63));  // keep j > i
            if (sup && jg > i) tbits |= (1ull << (i & 63));
        }
        if (lane == 0) gmask[(((size_t)(base + i)) << 4) + w] = bits;
    }
    if (wg == rg) tdiag[((size_t)p << 10) + (w << 6) + lane] = tbits;
}

// ---------------- NMS phase 2: bulk mask->LDS + word-level fixpoint greedy scan --------
// Per group: the greedy accepted set A is the unique fixpoint of A = alive & ~K(A),
// K(A)_l = (tdiag_l & A) != 0 (tdiag strictly upper-triangular). Iterating converges
// (bit l pinned after <= l iters); sparse suppressions -> ~2-3 iterations. Emission is
// parallel (pos = ns + popc(A & below)). No per-accept serial chain at all.
__global__ __launch_bounds__(1024) void scan_kernel(
    const unsigned long long* __restrict__ gmask,
    const unsigned long long* __restrict__ tdiag,
    const float4* __restrict__ cbox, const float* __restrict__ csc,
    float* __restrict__ svbox, float* __restrict__ svsc, int* __restrict__ svcnt) {
    __shared__ unsigned long long lm[CAP * LMS];
    __shared__ float ssc[CAP];
    __shared__ unsigned short survL[CAP];
    __shared__ int s_ns;
    const int p = blockIdx.x, tid = threadIdx.x;
    const int base = p * CAP;

    {   // copy mask -> LDS with 17-word row stride (row-gather reads spread over banks)
        const ulonglong2* g2 = (const ulonglong2*)(gmask + ((size_t)base << 4));
#pragma unroll
        for (int c = 0; c < 8; ++c) {
            ulonglong2 v = g2[c * 1024 + tid];
            const int gw = (c * 1024 + tid) << 1;
            const int row = gw >> 4, w = gw & 15;
            lm[row * LMS + w] = v.x;
            lm[row * LMS + w + 1] = v.y;
        }
        ssc[tid] = csc[base + tid];
    }
    __syncthreads();

    if (tid < 64) {
        const int lane = tid;
        const unsigned long long* td = tdiag + ((size_t)p << 10);
        unsigned long long tg = td[lane];          // group 0 transposed diagonal
        const unsigned long long mybit = 1ull << lane;
        const unsigned long long below = mybit - 1ull;
        int ns = 0;
        for (int g = 0; g < 16; ++g) {
            unsigned long long tgn = (g < 15) ? td[((g + 1) << 6) + lane] : 0ull;
            unsigned long long wv = __ballot(ssc[(g << 6) + lane] <= 0.f);
            // cross-group suppression: OR word g over all prior accepts (off-chain MLP)
            unsigned long long a0 = 0, a1 = 0, a2 = 0, a3 = 0;
            int j = lane;
            for (; j + 192 < ns; j += 256) {
                int r0 = survL[j], r1 = survL[j + 64];
                int r2 = survL[j + 128], r3 = survL[j + 192];
                a0 |= lm[r0 * LMS + g];
                a1 |= lm[r1 * LMS + g];
                a2 |= lm[r2 * LMS + g];
                a3 |= lm[r3 * LMS + g];
            }
            for (; j < ns; j += 64) a0 |= lm[((int)survL[j]) * LMS + g];
            unsigned long long accw = (a0 | a1) | (a2 | a3);
#pragma unroll
            for (int d2 = 1; d2 < 64; d2 <<= 1)
                accw |= (unsigned long long)__shfl_xor((unsigned long long)accw, d2);

            const unsigned long long alive = ~(wv | accw);
            unsigned long long A = alive;
#pragma unroll 1
            for (int it = 0; it < 64; ++it) {      // fixpoint -> exact greedy set
                bool kill = (tg & A) != 0ull;
                unsigned long long An = alive & ~__ballot(kill);
                if (An == A) break;
                A = An;
            }
            if (A & mybit)                          // parallel, order-preserving emission
                survL[ns + __popcll(A & below)] = (unsigned short)((g << 6) + lane);
            ns += __popcll(A);
            tg = tgn;
        }
        if (lane == 0) s_ns = ns;
    }
    __syncthreads();

    const int ns = s_ns;
    for (int s = tid; s < ns; s += 1024) {
        int r = survL[s];
        svsc[base + s] = ssc[r];
        *(float4*)(svbox + ((size_t)(base + s)) * 4) = cbox[base + r];
    }
    if (tid == 0) svcnt[p] = ns;
}

// ---------------- merge 5 survivor lists per image by score (ties -> lower level) ----------------
__global__ __launch_bounds__(256) void merge_kernel(
    const float* __restrict__ svbox, const float* __restrict__ svsc,
    const int* __restrict__ svcnt, float* __restrict__ out) {
    __shared__ float sls[NLVL][CAP];
    __shared__ int scnt[NLVL];
    const int img = blockIdx.x, tid = threadIdx.x;
    if (tid < NLVL) scnt[tid] = svcnt[img * NLVL + tid];
    __syncthreads();
    for (int l = 0; l < NLVL; ++l) {
        int c = scnt[l];
        for (int i = tid; i < c; i += 256) sls[l][i] = svsc[(img * NLVL + l) * CAP + i];
    }
    __syncthreads();
    for (int l = 0; l < NLVL; ++l) {
        int c = scnt[l];
        for (int i = tid; i < c; i += 256) {
            float s = sls[l][i];
            int pos = i;
            for (int m = 0; m < NLVL; ++m) {
                if (m == l) continue;
                int n2 = scnt[m];
                int lo = 0, hi = n2;
                if (m < l) {
                    while (lo < hi) { int mid = (lo + hi) >> 1; if (sls[m][mid] >= s) lo = mid + 1; else hi = mid; }
                } else {
                    while (lo < hi) { int mid = (lo + hi) >> 1; if (sls[m][mid] > s)  lo = mid + 1; else hi = mid; }
                }
                pos += lo;
            }
            if (pos < POST_N) {
                int src = (img * NLVL + l) * CAP + i;
                float* o = out + ((size_t)img * POST_N + pos) * 5;
                o[0] = svbox[(size_t)src * 4 + 0];
                o[1] = svbox[(size_t)src * 4 + 1];
                o[2] = svbox[(size_t)src * 4 + 2];
                o[3] = svbox[(size_t)src * 4 + 3];
                o[4] = s;
            }
        }
    }
}

extern "C" void kernel_launch(void* const* d_in, const int* in_sizes, int n_in,
                              void* d_out, int out_size, void* d_ws, size_t ws_size,
                              hipStream_t stream) {
    const float* obj     = (const float*)d_in[0];
    const float* deltas  = (const float*)d_in[1];
    const float* anchors = (const float*)d_in[2];
    float* out = (float*)d_out;

    char* w = (char*)d_ws;
    size_t off = 0;
    auto alloc = [&](size_t bytes) -> void* {
        void* pp = w + off;
        off += (bytes + 511) & ~(size_t)511;
        return pp;
    };
    unsigned* ghist = (unsigned*)alloc((size_t)NPROB * HBINS * 4);
    unsigned* b1buf = (unsigned*)alloc((size_t)NPROB * 4);
    int*      ccnt  = (int*)alloc((size_t)NPROB * 4);
    unsigned long long* cand = (unsigned long long*)alloc((size_t)NPROB * CCAP * 8);
    float4*   cbox  = (float4*)alloc((size_t)NPROB * CAP * 16);
    float*    csc   = (float*)alloc((size_t)NPROB * CAP * 4);
    unsigned long long* gmask = (unsigned long long*)alloc((size_t)NPROB * CAP * 16 * 8);
    unsigned long long* tdiag = (unsigned long long*)alloc((size_t)NPROB * CAP * 8);
    float* svbox = (float*)alloc((size_t)NPROB * CAP * 16);
    float* svsc  = (float*)alloc((size_t)NPROB * CAP * 4);
    int*   svcnt = (int*)alloc((size_t)NPROB * 4);
    if (off > ws_size) return;  // fail cleanly (output stays poisoned -> visible failure)

    hipMemsetAsync(ghist, 0, (size_t)NPROB * HBINS * 4, stream);
    hipMemsetAsync(ccnt, 0, (size_t)NPROB * 4, stream);
    hipMemsetAsync(csc, 0, (size_t)NPROB * CAP * 4, stream);
    hipMemsetAsync(d_out, 0, (size_t)out_size * sizeof(float), stream);

    hist_kernel<<<NBATCH * NCHUNK, 256, 0, stream>>>(obj, ghist);
    pick1_kernel<<<NPROB, 256, 0, stream>>>(ghist, b1buf);
    compact_kernel<<<NBATCH * NCHUNK, 256, 0, stream>>>(obj, b1buf, ccnt, cand);
    rankdec_kernel<<<NPROB * 16, 256, 0, stream>>>(cand, ccnt, obj, deltas, anchors,
                                                   cbox, csc);
    mask_kernel<<<NPROB * 10, 256, 0, stream>>>(cbox, gmask, tdiag);
    scan_kernel<<<NPROB, 1024, 0, stream>>>(gmask, tdiag, cbox, csc, svbox, svsc, svcnt);
    merge_kernel<<<NBATCH, 256, 0, stream>>>(svbox, svsc, svcnt, out);
}